// Round 5
// baseline (865.363 us; speedup 1.0000x reference)
//
#include <hip/hip_runtime.h>

#define MDIM 512
#define NDIM 8192
#define KDIM 8192
#define BK 32  // k per phase

typedef short v8s __attribute__((ext_vector_type(8)));
typedef float v4f __attribute__((ext_vector_type(4)));
typedef int   v4i __attribute__((ext_vector_type(4)));

#define GLDS16(g, l)                                                    \
  __builtin_amdgcn_global_load_lds(                                     \
      (const __attribute__((address_space(1))) void*)(g),               \
      (__attribute__((address_space(3))) void*)(l), 16, 0, 0)
#define SB __builtin_amdgcn_sched_barrier(0)

__device__ __forceinline__ unsigned pack_bf2(float a, float b) {
  unsigned ia = __builtin_bit_cast(unsigned, a);
  unsigned ib = __builtin_bit_cast(unsigned, b);
  return __builtin_amdgcn_perm(ib, ia, 0x07060302u);  // bf16 trunc pair
}
__device__ __forceinline__ unsigned pack_bf2_rnd(float a, float b) {
  unsigned ia = __builtin_bit_cast(unsigned, a) + 0x8000u;
  unsigned ib = __builtin_bit_cast(unsigned, b) + 0x8000u;
  return __builtin_amdgcn_perm(ib, ia, 0x07060302u);
}

__device__ __forceinline__ int swz4(int r) { return (r ^ (r >> 2)) & 3; }

// x fp32 -> bf16 into ws, tiled [4 mt][256 ktg][512 units]*8elem with the
// 4-slot XOR swizzle PRE-APPLIED so the gemm's linear global_load_lds lands
// the swizzled layout (glds dest must be linear; permute the source).
__global__ __launch_bounds__(256) void cvt_x_kernel(const float* __restrict__ x,
                                                    short* __restrict__ xb) {
  const int g = blockIdx.x * 256 + threadIdx.x;  // global 16B-unit id
  const int mt = g >> 17;
  const int rem = g & 131071;
  const int ktg = rem >> 9;
  const int u = rem & 511;
  const int row = u >> 2;
  const int q = (u & 3) ^ swz4(row);
  const float* src = x + (size_t)(mt * 128 + row) * KDIM + ktg * BK + q * 8;
  v4f f0 = *(const v4f*)src;
  v4f f1 = *(const v4f*)(src + 4);
  v4i o;
  o[0] = pack_bf2_rnd(f0[0], f0[1]);
  o[1] = pack_bf2_rnd(f0[2], f0[3]);
  o[2] = pack_bf2_rnd(f1[0], f1[1]);
  o[3] = pack_bf2_rnd(f1[2], f1[3]);
  *(v4i*)(xb + (size_t)g * 8) = o;
}

template <int KS>
__global__ __launch_bounds__(256) void reduce_kernel(const float* __restrict__ p,
                                                     float* __restrict__ out) {
  const size_t i = ((size_t)blockIdx.x * 256 + threadIdx.x) * 4;
  v4f a = *(const v4f*)(p + i);
#pragma unroll
  for (int s = 1; s < KS; ++s) a += *(const v4f*)(p + (size_t)s * MDIM * NDIM + i);
  *(v4f*)(out + i) = a;
}

// Fused dequant GEMM. KS-way split-K, grid 256*KS, 32KB LDS -> 4 blocks/CU.
// A via global_load_lds from pre-swizzled xb; B via 2-named-set register
// pipeline with hand-counted vmcnt (never drained to 0 in the loop).
template <int KS>
__global__ __launch_bounds__(256, 4) void gemm_q_kernel(
    const short* __restrict__ xb, const int* __restrict__ wq,
    const float* __restrict__ wsc, float* __restrict__ outp) {
  constexpr int NKT = KDIM / KS / BK;  // 64 / 128 / 256 (even)
  __shared__ short lA[2][128 * BK];
  __shared__ short lB[2][128 * BK];

  // XCD-aware bijective swizzle: XCD x owns nt in [8x,8x+8) with all mt,kh
  // -> each weight line served to 4 mt-blocks from that XCD's L2.
  const int b = blockIdx.x;
  const int s = (b & 7) * (32 * KS) + (b >> 3);
  const int mt = s & 3;
  const int kh = (s >> 2) & (KS - 1);
  const int nt = s / (4 * KS);
  const int m0 = mt * 128, n0 = nt * 128;
  const int kbase = kh * (KDIM / KS);
  const int ktg0 = kbase / BK;  // global k-step base

  const int t = threadIdx.x;
  const int w = t >> 6, l = t & 63;
  const int wm = (w >> 1) * 64, wn = (w & 1) * 64;

  // B staging geometry: thread t covers row br_=t>>1 (0..127), k-units
  // q = 2*bh, 2*bh+1 (bh = t&1) -> 16 ints, 4 dwordx4 loads.
  const int br_ = t >> 1;
  const int bh = t & 1;
  const int bso0 = br_ * BK + (((2 * bh) ^ swz4(br_)) << 3);
  const int bso1 = br_ * BK + (((2 * bh + 1) ^ swz4(br_)) << 3);
  const int* gBt = wq + (size_t)(n0 + br_) * KDIM + kbase + bh * 16;

  v4f acc[4][4] = {};
  v4i sb0[4], sb1[4];  // named B prefetch sets (compile-time indexed only)

  auto issueB = [&](int ktl, v4i (&br)[4]) {
    const int* gp = gBt + ktl * BK;
#pragma unroll
    for (int h = 0; h < 4; ++h) br[h] = *(const v4i*)(gp + h * 4);
  };
  auto issueA = [&](int ktl, int buf) {
    const short* gA = xb + ((size_t)(mt * 256 + ktg0 + ktl) * 512) * 8;
#pragma unroll
    for (int it = 0; it < 2; ++it) {
      const int ub = it * 256 + w * 64;  // wave-uniform 16B-unit base
      GLDS16(gA + (size_t)(ub + l) * 8, &lA[buf][ub * 8]);
    }
  };
  auto stage = [&](v4i (&br)[4], int buf, float sc) {
    v4i o;
    o[0] = pack_bf2(sc * (float)br[0][0], sc * (float)br[0][1]);
    o[1] = pack_bf2(sc * (float)br[0][2], sc * (float)br[0][3]);
    o[2] = pack_bf2(sc * (float)br[1][0], sc * (float)br[1][1]);
    o[3] = pack_bf2(sc * (float)br[1][2], sc * (float)br[1][3]);
    *(v4i*)&lB[buf][bso0] = o;
    o[0] = pack_bf2(sc * (float)br[2][0], sc * (float)br[2][1]);
    o[1] = pack_bf2(sc * (float)br[2][2], sc * (float)br[2][3]);
    o[2] = pack_bf2(sc * (float)br[3][0], sc * (float)br[3][1]);
    o[3] = pack_bf2(sc * (float)br[3][2], sc * (float)br[3][3]);
    *(v4i*)&lB[buf][bso1] = o;
  };
  auto compute = [&](int buf) {
    const int q = l >> 4;
    v8s af[4], bq[4];
#pragma unroll
    for (int i = 0; i < 4; ++i) {
      const int ra = wm + i * 16 + (l & 15);
      af[i] = *(const v8s*)&lA[buf][ra * BK + ((q ^ swz4(ra)) << 3)];
      const int rb = wn + i * 16 + (l & 15);
      bq[i] = *(const v8s*)&lB[buf][rb * BK + ((q ^ swz4(rb)) << 3)];
    }
#pragma unroll
    for (int i = 0; i < 4; ++i)
#pragma unroll
      for (int j = 0; j < 4; ++j)
        acc[i][j] = __builtin_amdgcn_mfma_f32_16x16x32_bf16(
            af[i], bq[j], acc[i][j], 0, 0, 0);
  };
  auto scale_of = [&](int ktl) {  // 128-k scale block = 4 phases
    return wsc[nt * 64 + ((ktg0 + ktl) >> 2)];
  };

  // prologue: A(0)->buf0 (glds), B(0)->s0, B(1)->s1; stage tile 0
  issueA(0, 0); SB;
  issueB(0, sb0); SB;
  issueB(1, sb1); SB;
  stage(sb0, 0, scale_of(0));
  SB;
  asm volatile("s_waitcnt vmcnt(4) lgkmcnt(0)" ::: "memory");  // A0+B0 done
  SB; __builtin_amdgcn_s_barrier(); SB;

#pragma unroll 1
  for (int kt = 0; kt < NKT; kt += 2) {
    // even phase: compute tile kt (buf0). In flight entering: B(kt+1):4
    issueA(kt + 1, 1); SB;
    if (kt + 2 < NKT) issueB(kt + 2, sb0);
    SB;
    compute(0);
    stage(sb1, 1, scale_of(kt + 1));  // compiler-counted wait on B(kt+1)
    SB;
    if (kt + 2 < NKT)
      asm volatile("s_waitcnt vmcnt(4) lgkmcnt(0)" ::: "memory");  // A done
    else
      asm volatile("s_waitcnt vmcnt(0) lgkmcnt(0)" ::: "memory");
    SB; __builtin_amdgcn_s_barrier(); SB;

    // odd phase: compute tile kt+1 (buf1). Entering: B(kt+2):4
    if (kt + 2 < NKT) {
      issueA(kt + 2, 0); SB;
      if (kt + 3 < NKT) issueB(kt + 3, sb1);
      SB;
      compute(1);
      stage(sb0, 0, scale_of(kt + 2));
      SB;
      if (kt + 3 < NKT)
        asm volatile("s_waitcnt vmcnt(4) lgkmcnt(0)" ::: "memory");
      else
        asm volatile("s_waitcnt vmcnt(0) lgkmcnt(0)" ::: "memory");
      SB; __builtin_amdgcn_s_barrier(); SB;
    } else {
      compute(1);  // final tile
    }
  }

  float* dst = outp + (KS > 1 ? (size_t)kh * MDIM * NDIM : 0);
#pragma unroll
  for (int i = 0; i < 4; ++i) {
#pragma unroll
    for (int j = 0; j < 4; ++j) {
      const int mrow = m0 + wm + i * 16 + (l >> 4) * 4;
      const int ocol = n0 + wn + j * 16 + (l & 15);
#pragma unroll
      for (int r = 0; r < 4; ++r)
        dst[(size_t)(mrow + r) * NDIM + ocol] = acc[i][j][r];
    }
  }
}

extern "C" void kernel_launch(void* const* d_in, const int* in_sizes, int n_in,
                              void* d_out, int out_size, void* d_ws,
                              size_t ws_size, hipStream_t stream) {
  const float* x = (const float*)d_in[0];
  const int* wq = (const int*)d_in[1];
  const float* wsc = (const float*)d_in[2];
  float* out = (float*)d_out;

  const size_t xb_bytes = (size_t)MDIM * KDIM * sizeof(short);  // 8 MB
  const size_t pslice = (size_t)MDIM * NDIM * sizeof(float);    // 16 MB

  short* xb = (short*)d_ws;
  float* part = (float*)((char*)d_ws + xb_bytes);
  cvt_x_kernel<<<dim3((MDIM * KDIM) / (256 * 8)), dim3(256), 0, stream>>>(x, xb);
  if (ws_size >= xb_bytes + 4 * pslice) {
    gemm_q_kernel<4><<<dim3(1024), dim3(256), 0, stream>>>(xb, wq, wsc, part);
    reduce_kernel<4><<<dim3((MDIM * NDIM) / (256 * 4)), dim3(256), 0, stream>>>(part, out);
  } else if (ws_size >= xb_bytes + 2 * pslice) {
    gemm_q_kernel<2><<<dim3(512), dim3(256), 0, stream>>>(xb, wq, wsc, part);
    reduce_kernel<2><<<dim3((MDIM * NDIM) / (256 * 4)), dim3(256), 0, stream>>>(part, out);
  } else {
    gemm_q_kernel<1><<<dim3(256), dim3(256), 0, stream>>>(xb, wq, wsc, out);
  }
}

// Round 6
// 167.368 us; speedup vs baseline: 5.1704x; 5.1704x over previous
//
#include <hip/hip_runtime.h>

#define MDIM 512
#define NDIM 8192
#define KDIM 8192
#define BM 128
#define BN 64
#define BK 64

typedef short v8s __attribute__((ext_vector_type(8)));
typedef float v4f __attribute__((ext_vector_type(4)));
typedef int   v4i __attribute__((ext_vector_type(4)));

#define GLDS16(g, l)                                                    \
  __builtin_amdgcn_global_load_lds(                                     \
      (const __attribute__((address_space(1))) void*)(g),               \
      (__attribute__((address_space(3))) void*)(l), 16, 0, 0)
#define SB __builtin_amdgcn_sched_barrier(0)

// pack two f32 into two bf16 by truncation (exact for ints |v|<=255)
__device__ __forceinline__ unsigned pack_bf2(float a, float b) {
  unsigned ia = __builtin_bit_cast(unsigned, a);
  unsigned ib = __builtin_bit_cast(unsigned, b);
  return __builtin_amdgcn_perm(ib, ia, 0x07060302u);
}
// round-to-nearest-ish for x
__device__ __forceinline__ unsigned pack_bf2_rnd(float a, float b) {
  unsigned ia = __builtin_bit_cast(unsigned, a) + 0x8000u;
  unsigned ib = __builtin_bit_cast(unsigned, b) + 0x8000u;
  return __builtin_amdgcn_perm(ib, ia, 0x07060302u);
}

// x fp32 -> bf16, tiled [4 mt][128 ktg][1024 units]*8elem with the 8-slot
// XOR swizzle PRE-APPLIED (round-2 scheme, measured 0 conflicts): unit
// u = row*8 + slot'; holds k-elems (slot' ^ (row&7))*8.. of that row.
__global__ __launch_bounds__(256) void cvt_x_kernel(const float* __restrict__ x,
                                                    short* __restrict__ xb) {
  const int g = blockIdx.x * 256 + threadIdx.x;
  const int mt = g >> 17;
  const int rem = g & 131071;
  const int kt = rem >> 10;
  const int u = rem & 1023;
  const int row = u >> 3;
  const int slot = u & 7;
  const float* src =
      x + (size_t)(mt * BM + row) * KDIM + kt * BK + ((slot ^ (row & 7)) << 3);
  v4f f0 = *(const v4f*)src;
  v4f f1 = *(const v4f*)(src + 4);
  v4i o;
  o[0] = pack_bf2_rnd(f0[0], f0[1]);
  o[1] = pack_bf2_rnd(f0[2], f0[3]);
  o[2] = pack_bf2_rnd(f1[0], f1[1]);
  o[3] = pack_bf2_rnd(f1[2], f1[3]);
  *(v4i*)(xb + (size_t)g * 8) = o;
}

template <int KS>
__global__ __launch_bounds__(256) void reduce_kernel(const float* __restrict__ p,
                                                     float* __restrict__ out) {
  const size_t i = ((size_t)blockIdx.x * 256 + threadIdx.x) * 4;
  v4f a = *(const v4f*)(p + i);
#pragma unroll
  for (int s = 1; s < KS; ++s) a += *(const v4f*)(p + (size_t)s * MDIM * NDIM + i);
  *(v4f*)(out + i) = a;
}

// Fused dequant GEMM, m97-style single-LDS-buffer 2-barrier loop.
// A: bf16 via glds from pre-swizzled xb. B: RAW int32 via glds with the
// 16-slot bank swizzle folded into the per-lane GLOBAL source address
// (linear LDS dest). Dequant at accumulator level: weights exact in bf16,
// facc += s * acc every k128 block. No ds_writes, no staging VALU.
template <int KS>
__global__ __launch_bounds__(256, 3) void gemm_q_kernel(
    const short* __restrict__ xb, const int* __restrict__ wq,
    const float* __restrict__ wsc, float* __restrict__ outp) {
  constexpr int NKT = KDIM / KS / BK;  // 64 (KS=2) / 128 (KS=1)
  __shared__ short lA[BM * BK];  // 16KB, rows 128B, 8-slot XOR swizzle
  __shared__ int lB[BN * BK];    // 16KB, rows 256B, 16-slot XOR swizzle

  // XCD-aware: XCD c owns nt in [c*16, c*16+16) with all mt,kh resident ->
  // each weight line read once from HBM, shared 4x (mt) via that XCD's L2.
  const int b = blockIdx.x;
  const int c = b & 7;
  const int s = b >> 3;
  const int mt = s & 3;
  const int kh = (KS > 1) ? ((s >> 2) & (KS - 1)) : 0;
  const int nt = c * 16 + (s >> (KS > 1 ? 3 : 2));
  const int m0 = mt * BM, n0 = nt * BN;
  const int kints0 = kh * (KDIM / KS);  // k base (ints) for B
  const int ktg0 = kh * NKT;            // k-tile base for A layout / scales

  const int t = threadIdx.x;
  const int w = t >> 6, l = t & 63;
  const int wm = (w >> 1) * 64;  // wave tile 64m x 32n
  const int wn = (w & 1) * 32;

  // Per-lane glds source bases (it = 0..3, g = it*4 + w):
  // A: unit = (g*64 + l); src = xb[mt][ktg][unit] (pre-swizzled layout)
  // B: v = g*64 + l; row r = v>>4; src slot = (v&15) ^ (r&15)
  const short* aSrc[4];
  const int* bSrc[4];
#pragma unroll
  for (int it = 0; it < 4; ++it) {
    const int g = it * 4 + w;
    aSrc[it] = xb + ((size_t)(mt * 128 + ktg0) * 1024 + g * 64 + l) * 8;
    const int v = g * 64 + l;
    const int r = v >> 4;
    bSrc[it] = wq + (size_t)(n0 + r) * KDIM + kints0 + (((v & 15) ^ (r & 15)) << 2);
  }

  v4f acc[4][2] = {};
  v4f facc[4][2] = {};

#pragma unroll 1
  for (int ktl = 0; ktl < NKT; ++ktl) {
    // barrier A: all waves done reading LDS from previous phase
    SB;
    __builtin_amdgcn_s_barrier();
    SB;
    // issue 8 glds (4 A + 4 B), 1KB lane-dense each
#pragma unroll
    for (int it = 0; it < 4; ++it) {
      const int g = it * 4 + w;
      GLDS16(aSrc[it] + (size_t)ktl * 8192, &lA[g * 512]);
      GLDS16(bSrc[it] + ktl * 64, &lB[g * 256]);
    }
    SB;
    asm volatile("s_waitcnt vmcnt(0)" ::: "memory");
    SB;
    __builtin_amdgcn_s_barrier();  // barrier B: tile fully in LDS
    SB;

    // compute: raw int32 -> bf16 (exact) -> MFMA
#pragma unroll
    for (int kk = 0; kk < 2; ++kk) {
      v8s af[4];
#pragma unroll
      for (int i = 0; i < 4; ++i) {
        const int ra = wm + i * 16 + (l & 15);
        const int sl = (kk * 4 + (l >> 4)) ^ (ra & 7);
        af[i] = *(const v8s*)&lA[ra * 64 + sl * 8];
      }
      v8s bq[2];
#pragma unroll
      for (int j = 0; j < 2; ++j) {
        const int rb = wn + j * 16 + (l & 15);
        const int sl0 = kk * 8 + (l >> 4) * 2;
        v4i r0 = *(const v4i*)&lB[(rb * 16 + (sl0 ^ (rb & 15))) * 4];
        v4i r1 = *(const v4i*)&lB[(rb * 16 + ((sl0 + 1) ^ (rb & 15))) * 4];
        v4i o;
        o[0] = pack_bf2((float)r0[0], (float)r0[1]);
        o[1] = pack_bf2((float)r0[2], (float)r0[3]);
        o[2] = pack_bf2((float)r1[0], (float)r1[1]);
        o[3] = pack_bf2((float)r1[2], (float)r1[3]);
        bq[j] = __builtin_bit_cast(v8s, o);
      }
#pragma unroll
      for (int i = 0; i < 4; ++i)
#pragma unroll
        for (int j = 0; j < 2; ++j)
          acc[i][j] = __builtin_amdgcn_mfma_f32_16x16x32_bf16(
              af[i], bq[j], acc[i][j], 0, 0, 0);
    }

    // accumulator-level dequant once per k128 scale block (= 2 K-steps)
    if (ktl & 1) {
      const float sc = wsc[(nt >> 1) * 64 + kh * (NKT / 2) + (ktl >> 1)];
#pragma unroll
      for (int i = 0; i < 4; ++i)
#pragma unroll
        for (int j = 0; j < 2; ++j) {
          facc[i][j] += sc * acc[i][j];
          acc[i][j] = v4f{0.f, 0.f, 0.f, 0.f};
        }
    }
  }

  float* dst = outp + (KS > 1 ? (size_t)kh * MDIM * NDIM : 0);
#pragma unroll
  for (int i = 0; i < 4; ++i) {
#pragma unroll
    for (int j = 0; j < 2; ++j) {
      const int mrow = m0 + wm + i * 16 + (l >> 4) * 4;
      const int ocol = n0 + wn + j * 16 + (l & 15);
#pragma unroll
      for (int r = 0; r < 4; ++r)
        dst[(size_t)(mrow + r) * NDIM + ocol] = facc[i][j][r];
    }
  }
}

extern "C" void kernel_launch(void* const* d_in, const int* in_sizes, int n_in,
                              void* d_out, int out_size, void* d_ws,
                              size_t ws_size, hipStream_t stream) {
  const float* x = (const float*)d_in[0];
  const int* wq = (const int*)d_in[1];
  const float* wsc = (const float*)d_in[2];
  float* out = (float*)d_out;

  const size_t xb_bytes = (size_t)MDIM * KDIM * sizeof(short);  // 8 MB
  const size_t pslice = (size_t)MDIM * NDIM * sizeof(float);    // 16 MB

  short* xb = (short*)d_ws;
  float* part = (float*)((char*)d_ws + xb_bytes);
  cvt_x_kernel<<<dim3((MDIM * KDIM) / (256 * 8)), dim3(256), 0, stream>>>(x, xb);
  if (ws_size >= xb_bytes + 2 * pslice) {
    gemm_q_kernel<2><<<dim3(1024), dim3(256), 0, stream>>>(xb, wq, wsc, part);
    reduce_kernel<2><<<dim3((MDIM * NDIM) / (256 * 4)), dim3(256), 0, stream>>>(part, out);
  } else {
    gemm_q_kernel<1><<<dim3(512), dim3(256), 0, stream>>>(xb, wq, wsc, out);
  }
}

// Round 7
// 159.376 us; speedup vs baseline: 5.4297x; 1.0501x over previous
//
#include <hip/hip_runtime.h>

#define MDIM 512
#define NDIM 8192
#define KDIM 8192
#define BM 128
#define BN 64
#define KC 256           // k per staged chunk -> 1KB/row DRAM bursts
#define NCH (KDIM / KC)  // 32

typedef short v8s __attribute__((ext_vector_type(8)));
typedef float v4f __attribute__((ext_vector_type(4)));
typedef int   v4i __attribute__((ext_vector_type(4)));
typedef int   v2i __attribute__((ext_vector_type(2)));

#define SB __builtin_amdgcn_sched_barrier(0)

// pack two f32 into two bf16, round-to-nearest-ish (+0x8000 pre-truncate)
__device__ __forceinline__ unsigned pack_bf2_rnd(float a, float b) {
  unsigned ia = __builtin_bit_cast(unsigned, a) + 0x8000u;
  unsigned ib = __builtin_bit_cast(unsigned, b) + 0x8000u;
  return __builtin_amdgcn_perm(ib, ia, 0x07060302u);
}

// x fp32 -> bf16, FRAGMENT-major: per (mt, ktg64) 16KB tile of units
// unit = (rowblk*8 + slot)*16 + lane16, holding row = rowblk*16+lane16,
// k = ktg*64 + slot*8 .. +8. A wave's MFMA A-frag read is then one
// lane-dense 1KB global load. Reads here are fully coalesced; 16B writes
// scatter into 8MB (L2-absorbed).
__global__ __launch_bounds__(256) void cvt_x_kernel(const float* __restrict__ x,
                                                    short* __restrict__ xb) {
  const int tid = blockIdx.x * 256 + threadIdx.x;  // m*1024 + k8
  const int m = tid >> 10;
  const int k8 = tid & 1023;
  const float* src = x + (size_t)m * KDIM + k8 * 8;
  v4f f0 = *(const v4f*)src;
  v4f f1 = *(const v4f*)(src + 4);
  v4i o;
  o[0] = pack_bf2_rnd(f0[0], f0[1]);
  o[1] = pack_bf2_rnd(f0[2], f0[3]);
  o[2] = pack_bf2_rnd(f1[0], f1[1]);
  o[3] = pack_bf2_rnd(f1[2], f1[3]);
  const int mt = m >> 7, row = m & 127;
  const int ktg = k8 >> 3, slot = k8 & 7;
  const int unit = ((mt * 128 + ktg) << 10) + (((row >> 4) * 8 + slot) << 4) + (row & 15);
  *(v4i*)(xb + (size_t)unit * 8) = o;
}

// Fused dequant GEMM, chunked-K streaming:
//  - B: 32 chunks of 64 rows x 1KB CONTIGUOUS int32 bursts (DRAM-friendly),
//    scale folded during cvt, bf16 into double-buffered LDS (2x32KB),
//    ONE barrier per chunk (drain amortized over 4 MFMA sub-steps).
//  - A: fragment-major xb, per-wave lane-dense 1KB L2 reads, no LDS.
//  - KS=1: direct store, no partials/reduce.
__global__ __launch_bounds__(256, 2) void gemm_q_kernel(
    const short* __restrict__ xb, const int* __restrict__ wq,
    const float* __restrict__ wsc, float* __restrict__ out) {
  __shared__ short lB[2][BN * KC];  // 2 x 32KB

  // XCD swizzle: XCD c owns nt in [c*16, c*16+16) x all 4 mt -> weight
  // lines shared 4x in that XCD's L2.
  const int b = blockIdx.x;
  const int c = b & 7;
  const int s = b >> 3;  // 0..63
  const int mt = s & 3;
  const int nt = c * 16 + (s >> 2);
  const int m0 = mt * BM, n0 = nt * BN;

  const int t = threadIdx.x;
  const int w = t >> 6, l = t & 63;

  const int* wq_base = wq + (size_t)n0 * KDIM;
  const float* scb = wsc + (n0 >> 7) * 64;

  v4f acc[2][4] = {};

  // stage chunk kc -> lB[buf]: 16 passes, pass p loads row 4p+w's 1KB burst
  auto stage = [&](int kc, int buf) {
    const float s0 = scb[kc * 2];
    const float s1 = scb[kc * 2 + 1];
    const float sc = (l < 32) ? s0 : s1;  // lane's k-half of the chunk
#pragma unroll
    for (int p = 0; p < 16; ++p) {
      const int r = p * 4 + w;
      v4i q = *(const v4i*)(wq_base + (size_t)r * KDIM + kc * KC + l * 4);
      v2i o;
      o[0] = pack_bf2_rnd(sc * (float)q[0], sc * (float)q[1]);
      o[1] = pack_bf2_rnd(sc * (float)q[2], sc * (float)q[3]);
      const int byte = (l * 8) ^ ((r & 7) << 4);  // bank swizzle, 8B-aligned
      *(v2i*)((char*)&lB[buf][r * KC] + byte) = o;
    }
  };

  // compute chunk kc from lB[buf]: 4 sub-steps of k64
  auto compute = [&](int kc, int buf) {
#pragma unroll
    for (int ks = 0; ks < 4; ++ks) {
      const int ktg = kc * 4 + ks;
      const short* aB = xb + ((size_t)(mt * 128 + ktg) << 13);
      v8s af[2][2];
#pragma unroll
      for (int i = 0; i < 2; ++i)
#pragma unroll
        for (int kk = 0; kk < 2; ++kk)
          af[i][kk] = *(const v8s*)(
              aB + ((((w * 2 + i) * 8 + kk * 4 + (l >> 4)) << 4) + (l & 15)) * 8);
      v8s bq[4][2];
#pragma unroll
      for (int j = 0; j < 4; ++j) {
        const int rb = j * 16 + (l & 15);
#pragma unroll
        for (int kk = 0; kk < 2; ++kk) {
          const int byte = (ks * 128 + kk * 64 + (l >> 4) * 16) ^ ((rb & 7) << 4);
          bq[j][kk] = *(const v8s*)((const char*)&lB[buf][rb * KC] + byte);
        }
      }
#pragma unroll
      for (int kk = 0; kk < 2; ++kk)
#pragma unroll
        for (int i = 0; i < 2; ++i)
#pragma unroll
          for (int j = 0; j < 4; ++j)
            acc[i][j] = __builtin_amdgcn_mfma_f32_16x16x32_bf16(
                af[i][kk], bq[j][kk], acc[i][j], 0, 0, 0);
    }
  };

  stage(0, 0);
#pragma unroll 1
  for (int kc = 0; kc < NCH; ++kc) {
    const int cur = kc & 1;
    // publish stage(kc)'s ds_writes; free buf[cur^1] (all done computing kc-1)
    asm volatile("s_waitcnt lgkmcnt(0)" ::: "memory");
    SB;
    __builtin_amdgcn_s_barrier();
    SB;
    if (kc + 1 < NCH) stage(kc + 1, cur ^ 1);  // loads overlap compute below
    compute(kc, cur);
  }

#pragma unroll
  for (int i = 0; i < 2; ++i)
#pragma unroll
    for (int j = 0; j < 4; ++j) {
      const int mrow = m0 + w * 32 + i * 16 + (l >> 4) * 4;
      const int ocol = n0 + j * 16 + (l & 15);
#pragma unroll
      for (int r = 0; r < 4; ++r)
        out[(size_t)(mrow + r) * NDIM + ocol] = acc[i][j][r];
    }
}

extern "C" void kernel_launch(void* const* d_in, const int* in_sizes, int n_in,
                              void* d_out, int out_size, void* d_ws,
                              size_t ws_size, hipStream_t stream) {
  const float* x = (const float*)d_in[0];
  const int* wq = (const int*)d_in[1];
  const float* wsc = (const float*)d_in[2];
  float* out = (float*)d_out;

  short* xb = (short*)d_ws;  // 8 MB (ws >= 40 MB confirmed by earlier rounds)
  cvt_x_kernel<<<dim3((MDIM * KDIM) / (256 * 8)), dim3(256), 0, stream>>>(x, xb);
  gemm_q_kernel<<<dim3(512), dim3(256), 0, stream>>>(xb, wq, wsc, out);
}

// Round 8
// 138.684 us; speedup vs baseline: 6.2398x; 1.1492x over previous
//
#include <hip/hip_runtime.h>

#define MDIM 512
#define NDIM 8192
#define KDIM 8192

typedef float v4f __attribute__((ext_vector_type(4)));
typedef int   v4i __attribute__((ext_vector_type(4)));
typedef char  c16 __attribute__((ext_vector_type(16)));

#define GLDS16(g, l)                                                    \
  __builtin_amdgcn_global_load_lds(                                     \
      (const __attribute__((address_space(1))) void*)(g),               \
      (__attribute__((address_space(3))) void*)(l), 16, 0, 0)
#define SB __builtin_amdgcn_sched_barrier(0)

// Swizzled byte offset inside a tile of 64B rows (BK=64 int8): rows paired
// into 128B blocks of 8x16B slots; slot index XOR'd with row-pair. Same
// formula used by the producers (compress/quant write side) and the gemm
// (ds_read side); glds copies linearly in between (rule 21: both sides).
__device__ __forceinline__ int swb(int row, int g) {
  return ((row >> 1) << 7) + (((((row & 1) << 2) | g) ^ ((row >> 1) & 7)) << 4);
}

// wq int32 -> int8, frag-tiled w8[nt(128)][kt(128)][4096B], swizzled.
// Pure streaming: low-byte extract, no arithmetic. Source fully coalesced
// (each thread 64B dense, wave 4KB dense).
__global__ __launch_bounds__(256) void compress_w_kernel(
    const int* __restrict__ wq, char* __restrict__ w8) {
  const int tid = blockIdx.x * 256 + threadIdx.x;
  const int R = tid >> 9;      // weight row 0..8191
  const int k16 = tid & 511;   // 16-int group in row
  const int* src = wq + ((size_t)R << 13) + k16 * 16;
  v4i a[4];
#pragma unroll
  for (int h = 0; h < 4; ++h) a[h] = *(const v4i*)(src + h * 4);
  c16 q;
#pragma unroll
  for (int h = 0; h < 4; ++h) {
    q[h * 4 + 0] = (char)a[h][0];
    q[h * 4 + 1] = (char)a[h][1];
    q[h * 4 + 2] = (char)a[h][2];
    q[h * 4 + 3] = (char)a[h][3];
  }
  const int nt = R >> 6, r = R & 63;
  const int kt = k16 >> 2, g = k16 & 3;
  *(c16*)(w8 + ((size_t)(nt * 128 + kt) << 12) + swb(r, g)) = q;
}

// x fp32 -> int8 with per-row scale ax[m]; frag-tiled xq[mt(4)][kt(128)][8192B].
__global__ __launch_bounds__(256) void quant_x_kernel(
    const float* __restrict__ x, char* __restrict__ xq, float* __restrict__ ax) {
  const int m = blockIdx.x;
  const int t = threadIdx.x;
  const float* row = x + ((size_t)m << 13);
  v4f v[8];
  float mx = 0.f;
#pragma unroll
  for (int i = 0; i < 8; ++i) {
    v[i] = *(const v4f*)(row + t * 32 + i * 4);
#pragma unroll
    for (int r = 0; r < 4; ++r) mx = fmaxf(mx, fabsf(v[i][r]));
  }
#pragma unroll
  for (int d = 1; d < 64; d <<= 1) mx = fmaxf(mx, __shfl_xor(mx, d));
  __shared__ float smx[4];
  if ((t & 63) == 0) smx[t >> 6] = mx;
  __syncthreads();
  mx = fmaxf(fmaxf(smx[0], smx[1]), fmaxf(smx[2], smx[3]));
  const float inv = (mx > 0.f) ? 127.f / mx : 0.f;
  if (t == 0) ax[m] = mx / 127.f;
  const int mt = m >> 7, r = m & 127;
#pragma unroll
  for (int g2 = 0; g2 < 2; ++g2) {  // two 16-value groups per thread
    c16 q;
#pragma unroll
    for (int e = 0; e < 16; ++e) {
      const int idx = g2 * 4 + (e >> 2);
      float f = fminf(fmaxf(v[idx][e & 3] * inv, -127.f), 127.f);
      q[e] = (char)__float2int_rn(f);
    }
    const int k16 = t * 2 + g2;
    const int kt = k16 >> 2, g = k16 & 3;
    *(c16*)(xq + ((size_t)(mt * 128 + kt) << 13) + swb(r, g)) = q;
  }
}

template <int KS>
__global__ __launch_bounds__(256) void reduce_kernel(const float* __restrict__ p,
                                                     float* __restrict__ out) {
  const size_t i = ((size_t)blockIdx.x * 256 + threadIdx.x) * 4;
  v4f a = *(const v4f*)(p + i);
#pragma unroll
  for (int s = 1; s < KS; ++s) a += *(const v4f*)(p + (size_t)s * MDIM * NDIM + i);
  *(v4f*)(out + i) = a;
}

// Pure-i8 GEMM: BM=128, BN=64, BK=64, 4 waves (wave tile 64m x 32n).
// Raw int8 glds -> LDS (24KB dbuf) -> ds_read_b128 -> mfma_i32_16x16x64_i8.
// Scale at accumulator level per k128 block; ax at epilogue. No staging VALU.
template <int KS>
__global__ __launch_bounds__(256, 2) void gemm_i8_kernel(
    const char* __restrict__ xq, const char* __restrict__ w8,
    const float* __restrict__ wsc, const float* __restrict__ ax,
    float* __restrict__ outp) {
  constexpr int NKT = 128 / KS;  // K-phases per block (even)
  __shared__ char lA[2][8192];
  __shared__ char lB[2][4096];

  // XCD swizzle: XCD c owns nt range [c*16, c*16+16) x all mt,kh -> B tiles
  // shared 4x (mt) in that XCD's L2.
  const int b = blockIdx.x;
  const int c = b & 7;
  const int s = b >> 3;
  const int mt = s & 3;
  const int kh = (KS > 1) ? ((s >> 2) & (KS - 1)) : 0;
  const int nt = c * 16 + (s >> (KS > 1 ? 3 : 2));
  const int m0 = mt * 128, n0 = nt * 64;
  const int kt0 = kh * NKT;

  const int t = threadIdx.x;
  const int w = t >> 6, l = t & 63;
  const int wm = (w >> 1) * 64, wn = (w & 1) * 32;
  const int l15 = l & 15, q = l >> 4;

  const char* asrc = xq + ((size_t)(mt * 128 + kt0) << 13);
  const char* bsrc = w8 + ((size_t)(nt * 128 + kt0) << 12);

  v4i acc[4][2] = {};
  v4f facc[4][2] = {};

  auto issue = [&](int tt) {
    const int buf = tt & 1;
#pragma unroll
    for (int it = 0; it < 2; ++it) {
      const int ub = (it * 4 + w) * 64;  // wave-uniform 16B-unit base
      GLDS16(asrc + ((size_t)tt << 13) + (ub + l) * 16, &lA[buf][ub * 16]);
    }
    GLDS16(bsrc + ((size_t)tt << 12) + (w * 64 + l) * 16, &lB[buf][w * 1024]);
  };

  issue(0);
#pragma unroll 1
  for (int tt = 0; tt < NKT; ++tt) {
    const int cur = tt & 1;
    SB;
    __builtin_amdgcn_s_barrier();  // all waves done reading buf[cur^1]
    SB;
    if (tt + 1 < NKT) issue(tt + 1);  // -> buf[cur^1]
    SB;
    if (tt + 1 < NKT)
      asm volatile("s_waitcnt vmcnt(3)" ::: "memory");  // tile tt landed
    else
      asm volatile("s_waitcnt vmcnt(0)" ::: "memory");
    SB;
    __builtin_amdgcn_s_barrier();  // buf[cur] visible to all waves
    SB;

    v4i af[4], bq[2];
#pragma unroll
    for (int i = 0; i < 4; ++i)
      af[i] = *(const v4i*)&lA[cur][swb(wm + i * 16 + l15, q)];
#pragma unroll
    for (int j = 0; j < 2; ++j)
      bq[j] = *(const v4i*)&lB[cur][swb(wn + j * 16 + l15, q)];
#pragma unroll
    for (int i = 0; i < 4; ++i)
#pragma unroll
      for (int j = 0; j < 2; ++j)
        acc[i][j] = __builtin_amdgcn_mfma_i32_16x16x64_i8(
            af[i], bq[j], acc[i][j], 0, 0, 0);

    if (tt & 1) {  // per-k128 scale block: fold into f32 accumulator
      const float sc = wsc[(nt >> 1) * 64 + ((kt0 + tt) >> 1)];
#pragma unroll
      for (int i = 0; i < 4; ++i)
#pragma unroll
        for (int j = 0; j < 2; ++j) {
#pragma unroll
          for (int r = 0; r < 4; ++r) facc[i][j][r] += sc * (float)acc[i][j][r];
          acc[i][j] = v4i{0, 0, 0, 0};
        }
    }
  }

  float* dst = outp + ((KS > 1) ? (size_t)kh * MDIM * NDIM : 0);
#pragma unroll
  for (int i = 0; i < 4; ++i) {
#pragma unroll
    for (int j = 0; j < 2; ++j) {
      const int mrow = m0 + wm + i * 16 + (l >> 4) * 4;
      const int ocol = n0 + wn + j * 16 + l15;
#pragma unroll
      for (int r = 0; r < 4; ++r)
        dst[(size_t)(mrow + r) * NDIM + ocol] = ax[mrow + r] * facc[i][j][r];
    }
  }
}

extern "C" void kernel_launch(void* const* d_in, const int* in_sizes, int n_in,
                              void* d_out, int out_size, void* d_ws,
                              size_t ws_size, hipStream_t stream) {
  const float* x = (const float*)d_in[0];
  const int* wq = (const int*)d_in[1];
  const float* wsc = (const float*)d_in[2];
  float* out = (float*)d_out;

  const size_t W8 = (size_t)NDIM * KDIM;             // 64 MB
  const size_t XQ = (size_t)MDIM * KDIM;             // 4 MB
  const size_t AX = 65536;                           // 2 KB padded
  const size_t PS = (size_t)MDIM * NDIM * 4;         // 16 MB per partial

  char* w8 = (char*)d_ws;
  char* xq = (char*)d_ws + W8;
  float* ax = (float*)((char*)d_ws + W8 + XQ);
  float* part = (float*)((char*)d_ws + W8 + XQ + AX);

  compress_w_kernel<<<dim3((NDIM * (KDIM / 16)) / 256), dim3(256), 0, stream>>>(wq, w8);
  quant_x_kernel<<<dim3(MDIM), dim3(256), 0, stream>>>(x, xq, ax);

  if (ws_size >= W8 + XQ + AX + 2 * PS) {
    gemm_i8_kernel<2><<<dim3(1024), dim3(256), 0, stream>>>(xq, w8, wsc, ax, part);
    reduce_kernel<2><<<dim3((MDIM * NDIM) / (256 * 4)), dim3(256), 0, stream>>>(part, out);
  } else {
    gemm_i8_kernel<1><<<dim3(512), dim3(256), 0, stream>>>(xq, w8, wsc, ax, out);
  }
}